// Round 7
// baseline (437.491 us; speedup 1.0000x reference)
//
#include <hip/hip_runtime.h>

#define B_ 128
#define T_ 2048
#define H_ 128

typedef __attribute__((ext_vector_type(8))) short short8;
typedef __attribute__((ext_vector_type(4))) float f32x4;

__device__ __forceinline__ unsigned short f2b(float f) {
    unsigned int u = __float_as_uint(f);
    u += 0x7fffu + ((u >> 16) & 1u);   // RNE
    return (unsigned short)(u >> 16);
}
__device__ __forceinline__ short8 pack8(const float4 x, const float4 y) {
    short8 r;
    r[0] = (short)f2b(x.x); r[1] = (short)f2b(x.y);
    r[2] = (short)f2b(x.z); r[3] = (short)f2b(x.w);
    r[4] = (short)f2b(y.x); r[5] = (short)f2b(y.y);
    r[6] = (short)f2b(y.z); r[7] = (short)f2b(y.w);
    return r;
}
__device__ __forceinline__ float tanh_fast(float x) {
    x = fminf(fmaxf(x, -20.f), 20.f);
    float e = __expf(2.f * x);
    return (e - 1.f) / (e + 1.f);
}

// ---------------- Phase 0: amax[b] = max_t acc_w[b,t] ----------------
__global__ __launch_bounds__(256) void amax_kernel(
    const float* __restrict__ accw, float* __restrict__ amax_g)
{
    __shared__ float wred[4];
    const int b = blockIdx.x, tid = threadIdx.x;
    const float* p = accw + (size_t)b * T_ + tid * 8;
    float4 a0 = *(const float4*)p, a1 = *(const float4*)(p + 4);
    float m = fmaxf(fmaxf(fmaxf(a0.x, a0.y), fmaxf(a0.z, a0.w)),
                    fmaxf(fmaxf(a1.x, a1.y), fmaxf(a1.z, a1.w)));
    for (int d = 32; d >= 1; d >>= 1) m = fmaxf(m, __shfl_xor(m, d, 64));
    if ((tid & 63) == 0) wred[tid >> 6] = m;
    __syncthreads();
    if (tid == 0)
        amax_g[b] = fmaxf(fmaxf(wred[0], wred[1]), fmaxf(wred[2], wred[3]));
}

// ---------------- Phase 1 (fused): energy + online-softmax tile partials ----
// v7: 1024-thread blocks (16 waves) -> 2 blocks/CU x 16 waves = 32 waves/CU
//     (8/SIMD, was 4/SIMD). Tile = 256 rows (8 per b). LDS trimmed to 73.5 KB
//     (merged s/p buffer, 16-group float2 ctx partial) so 2 blocks still fit.
//     K-loop (depth-4 register pipeline + sched_barrier) unchanged from v6.
__global__ __launch_bounds__(1024, 8) void energy_kernel(
    const float* __restrict__ Hp,
    const float* __restrict__ Hd,
    const float* __restrict__ accw,
    const float* __restrict__ Wh,
    const float* __restrict__ Wd,
    const float* __restrict__ Wa,
    const float* __restrict__ ba_p,
    const float* __restrict__ beta_p,
    const float* __restrict__ amax_g,
    float* __restrict__ s_g,      // [B,T] scaled energies
    float* __restrict__ ml_g,     // [B,8,2] (m,l) per tile
    float* __restrict__ ctxp_g,   // [B,8,H] ctx partials
    int ntiles)                   // tiles of 256 rows
{
    __shared__ unsigned short Wpack[8 * 8 * 64 * 8];   // 64 KB [kt][nt][lane][8]
    __shared__ float Was[H_];                          // 512 B
    __shared__ float sp[256];                          // 1 KB (s then p, in place)
    __shared__ float red[16 * H_];                     // 8 KB
    __shared__ float mld[2];

    const int tid = threadIdx.x;

    // stage W_h (kt 0..3) and W_d (kt 4..7) into read-order bf16 LDS
    for (int i = tid; i < (H_ * H_) / 4; i += 1024) {
        int o  = i >> 5;
        int c4 = i & 31;
        float4 wh = *(const float4*)&Wh[o * H_ + c4 * 4];
        float4 wd = *(const float4*)&Wd[o * H_ + c4 * 4];
        uint2 ph, pdv;
        ph.x  = (unsigned)f2b(wh.x) | ((unsigned)f2b(wh.y) << 16);
        ph.y  = (unsigned)f2b(wh.z) | ((unsigned)f2b(wh.w) << 16);
        pdv.x = (unsigned)f2b(wd.x) | ((unsigned)f2b(wd.y) << 16);
        pdv.y = (unsigned)f2b(wd.z) | ((unsigned)f2b(wd.w) << 16);
        int nt   = o >> 4;
        int l15o = o & 15;
        int kth  = c4 >> 3;
        int lq   = (c4 >> 1) & 3;
        int half = (c4 & 1) * 4;
        int bh = ((kth * 8 + nt) * 64 + lq * 16 + l15o) * 8 + half;
        int bd = (((kth + 4) * 8 + nt) * 64 + lq * 16 + l15o) * 8 + half;
        *(uint2*)&Wpack[bh] = ph;
        *(uint2*)&Wpack[bd] = pdv;
    }
    if (tid < H_) Was[tid] = Wa[tid];
    __syncthreads();

    const float ba = ba_p[0];
    const float beta_pos = log1pf(__expf(beta_p[0]));

    const int wave = tid >> 6;     // 0..15
    const int lane = tid & 63;
    const int l15  = lane & 15;
    const int lq   = lane >> 4;

    const unsigned short* wb = Wpack + lane * 8;

    const size_t estep = (size_t)gridDim.x * 256 * H_;

    const int row0 = blockIdx.x * 256 + wave * 16;
    const float* pp = Hp + (size_t)(row0 + l15) * H_ + lq * 8;
    const float* pd = Hd + (size_t)(row0 + l15) * H_ + lq * 8;

    float4 abuf[8];
    #pragma unroll
    for (int c = 0; c < 4; c++) {
        abuf[2 * c]     = *(const float4*)(pp + c * 32);
        abuf[2 * c + 1] = *(const float4*)(pp + c * 32 + 4);
    }

    for (int tile = blockIdx.x; tile < ntiles; tile += gridDim.x) {
        __syncthreads();   // protect sp/red reuse across tile iterations

        const int b  = tile >> 3;          // 8 tiles of 256 per b
        const int t0 = (tile & 7) * 256;
        const size_t adv = (tile + (int)gridDim.x < ntiles) ? estep : 0;
        const float* ppn = pp + adv;

        f32x4 acc[8];
        #pragma unroll
        for (int nt = 0; nt < 8; nt++) acc[nt] = (f32x4){0.f, 0.f, 0.f, 0.f};

        #pragma unroll
        for (int kt = 0; kt < 8; kt++) {
            const int sl = kt & 3;
            short8 af = pack8(abuf[2 * sl], abuf[2 * sl + 1]);
            const float* s = (kt < 4) ? (pd + kt * 32) : (ppn + (kt - 4) * 32);
            abuf[2 * sl]     = *(const float4*)s;
            abuf[2 * sl + 1] = *(const float4*)(s + 4);
            #pragma unroll
            for (int nt = 0; nt < 8; nt++) {
                short8 bf = *(const short8*)(wb + kt * 4096 + nt * 512);
                acc[nt] = __builtin_amdgcn_mfma_f32_16x16x32_bf16(af, bf, acc[nt], 0, 0, 0);
            }
            __builtin_amdgcn_sched_barrier(0);
        }
        pp = ppn;
        pd += adv;

        float ep[4] = {0.f, 0.f, 0.f, 0.f};
        #pragma unroll
        for (int nt = 0; nt < 8; nt++) {
            const float wa = Was[nt * 16 + l15];
            #pragma unroll
            for (int r = 0; r < 4; r++) ep[r] += tanh_fast(acc[nt][r]) * wa;
        }
        #pragma unroll
        for (int m = 1; m < 16; m <<= 1) {
            #pragma unroll
            for (int r = 0; r < 4; r++) ep[r] += __shfl_xor(ep[r], m, 64);
        }
        if (l15 == 0) {
            // C/D: col = lane&15, row = lq*4 + r
            #pragma unroll
            for (int r = 0; r < 4; r++)
                sp[wave * 16 + lq * 4 + r] = ep[r] + ba;
        }
        __syncthreads();

        // scale by acceleration term, write s_g, keep s in sp
        if (tid < 256) {
            float a = accw[(size_t)b * T_ + t0 + tid];
            float invd = beta_pos / fmaxf(amax_g[b], 1e-6f);
            float s = (sp[tid] ) * (1.f + a * invd);
            sp[tid] = s;
            s_g[(size_t)b * T_ + t0 + tid] = s;
        }
        __syncthreads();

        // tile max over 256 (wave 0)
        if (wave == 0) {
            float m = fmaxf(fmaxf(sp[lane], sp[lane + 64]),
                            fmaxf(sp[lane + 128], sp[lane + 192]));
            for (int d = 32; d >= 1; d >>= 1) m = fmaxf(m, __shfl_xor(m, d, 64));
            if (lane == 0) mld[0] = m;
        }
        __syncthreads();
        const float mt = mld[0];
        if (tid < 256) sp[tid] = __expf(sp[tid] - mt);   // p in place
        __syncthreads();

        // tile sum (wave 0) -> write (m,l)
        if (wave == 0) {
            float l = (sp[lane] + sp[lane + 64]) + (sp[lane + 128] + sp[lane + 192]);
            for (int d = 32; d >= 1; d >>= 1) l += __shfl_xor(l, d, 64);
            if (lane == 0) {
                ml_g[(b * 8 + (tile & 7)) * 2 + 0] = mt;
                ml_g[(b * 8 + (tile & 7)) * 2 + 1] = l;
            }
        }

        // ctx partial: 16 groups of 64 threads; group g covers rows g*16..g*16+15,
        // thread (g, c2=tid&63) covers cols c2*2, c2*2+1 (float2, coalesced 512B/row)
        {
            const int g  = tid >> 6;
            const int c2 = tid & 63;
            const float* base = Hp + ((size_t)b * T_ + t0 + g * 16) * H_ + c2 * 2;
            float c0 = 0.f, c1 = 0.f;
            #pragma unroll
            for (int r = 0; r < 16; r++) {
                float pv = sp[g * 16 + r];
                float2 v = *(const float2*)(base + (size_t)r * H_);
                c0 += pv * v.x; c1 += pv * v.y;
            }
            red[g * H_ + c2 * 2 + 0] = c0;
            red[g * H_ + c2 * 2 + 1] = c1;
        }
        __syncthreads();
        if (tid < 128) {
            float s = 0.f;
            #pragma unroll
            for (int g = 0; g < 16; g++) s += red[g * H_ + tid];
            ctxp_g[((size_t)b * 8 + (tile & 7)) * H_ + tid] = s;
        }
    }
}

// ---------------- Phase 2: combine tile partials -> ctx, alpha ----------------
// grid = B; per b: M = max m_ti, L = sum exp(m_ti-M) l_ti;
// ctx = sum exp(m_ti-M)*ctxp_ti / L; alpha_t = exp(s_t - M)/L.
__global__ __launch_bounds__(256) void combine_kernel(
    const float* __restrict__ s_g,
    const float* __restrict__ ml_g,
    const float* __restrict__ ctxp_g,
    float* __restrict__ out_ctx,
    float* __restrict__ out_alpha)
{
    __shared__ float ml_s[16];
    const int b = blockIdx.x, tid = threadIdx.x;

    if (tid < 16) ml_s[tid] = ml_g[b * 16 + tid];
    __syncthreads();

    float M = -1e30f;
    #pragma unroll
    for (int i = 0; i < 8; i++) M = fmaxf(M, ml_s[2 * i]);
    float L = 0.f;
    #pragma unroll
    for (int i = 0; i < 8; i++) L += __expf(ml_s[2 * i] - M) * ml_s[2 * i + 1];
    const float invL = 1.f / L;

    if (tid < 128) {
        float s = 0.f;
        #pragma unroll
        for (int ti = 0; ti < 8; ti++)
            s += __expf(ml_s[2 * ti] - M) * ctxp_g[((size_t)b * 8 + ti) * H_ + tid];
        out_ctx[b * H_ + tid] = s * invL;
    }

    // alpha: 8 per thread, vectorized
    const float* ps = s_g + (size_t)b * T_ + tid * 8;
    float* pa = out_alpha + (size_t)b * T_ + tid * 8;
    float4 s0 = *(const float4*)ps, s1 = *(const float4*)(ps + 4);
    float4 a0, a1;
    a0.x = __expf(s0.x - M) * invL; a0.y = __expf(s0.y - M) * invL;
    a0.z = __expf(s0.z - M) * invL; a0.w = __expf(s0.w - M) * invL;
    a1.x = __expf(s1.x - M) * invL; a1.y = __expf(s1.y - M) * invL;
    a1.z = __expf(s1.z - M) * invL; a1.w = __expf(s1.w - M) * invL;
    *(float4*)pa = a0; *(float4*)(pa + 4) = a1;
}

extern "C" void kernel_launch(void* const* d_in, const int* in_sizes, int n_in,
                              void* d_out, int out_size, void* d_ws, size_t ws_size,
                              hipStream_t stream) {
    const float* Hp   = (const float*)d_in[0];
    const float* Hd   = (const float*)d_in[1];
    const float* accw = (const float*)d_in[2];
    const float* Wh   = (const float*)d_in[3];
    const float* Wd   = (const float*)d_in[4];
    const float* Wa   = (const float*)d_in[5];
    const float* ba   = (const float*)d_in[6];
    const float* beta = (const float*)d_in[7];

    float* s_ws    = (float*)d_ws;                     // B*T fp32 = 1 MB
    float* ctxp_ws = s_ws + B_ * T_;                   // B*8*H fp32 = 512 KB
    float* ml_ws   = ctxp_ws + B_ * 8 * H_;            // B*8*2 fp32 = 8 KB
    float* amax_ws = ml_ws + B_ * 8 * 2;               // B fp32

    float* out_ctx   = (float*)d_out;                  // [B,H]
    float* out_alpha = out_ctx + B_ * H_;              // [B,T]

    const int ntiles = (B_ * T_) / 256;   // 1024 tiles of 256 rows (8 per b)
    amax_kernel<<<B_, 256, 0, stream>>>(accw, amax_ws);
    energy_kernel<<<256, 1024, 0, stream>>>(Hp, Hd, accw, Wh, Wd, Wa, ba, beta,
                                            amax_ws, s_ws, ml_ws, ctxp_ws, ntiles);
    combine_kernel<<<B_, 256, 0, stream>>>(s_ws, ml_ws, ctxp_ws, out_ctx, out_alpha);
}